// Round 14
// baseline (544.677 us; speedup 1.0000x reference)
//
#include <hip/hip_runtime.h>
#include <hip/hip_bf16.h>

typedef __attribute__((ext_vector_type(8))) short short8;
typedef __attribute__((ext_vector_type(4))) short short4v;
typedef __attribute__((ext_vector_type(4))) float f32x4;

__device__ __forceinline__ short f2bf(float f) {
  union { __hip_bfloat16 h; short s; } u;
  u.h = __float2bfloat16(f);
  return u.s;
}

#define SCHED_FENCE() __builtin_amdgcn_sched_barrier(0)
#define EPS 68   // epilogue f32 row stride

// Streaming wave-GEMM: C[m0..+64, n0..+64] += A_bf16 * W_f32^T.
// NO LDS, NO barriers in the main loop. Explicit register double-buffer:
// issue iter b+1's 12 loads (4 A short8 + 8 W f32x4) into the idle set,
// sched_barrier, then consume the live set (cvt + 16 MFMA). The compiler's
// register-dependency waitcnt is a counted vmcnt(~12): next iter's loads
// stay in flight across the entire consume. ~12KB/wave outstanding.
// 8 waves of a block share one W panel (same n0) -> W is HBM-read once,
// re-reads hit same-CU L1/L2; raw s_barrier every 4 iters bounds drift.
template<int K>
__device__ __forceinline__ void sgemm_stream(
    const short* __restrict__ A,
    const float* __restrict__ W,
    const float* __restrict__ bias,
    float* __restrict__ C,
    int N, int m0, int n0, float* ep)
{
  const int lane = threadIdx.x & 63;
  const int l16  = lane & 15;
  const int lq   = lane >> 4;

  const short* ap = A + (size_t)(m0 + l16) * K + lq * 8;
  const float* wp = W + (size_t)(n0 + l16) * K + lq * 8;
  const size_t KS16 = (size_t)16 * K;

  f32x4 acc[4][4];
  #pragma unroll
  for (int i = 0; i < 4; ++i)
    #pragma unroll
    for (int j = 0; j < 4; ++j) {
      f32x4 z = {0.f, 0.f, 0.f, 0.f};
      acc[i][j] = z;
    }

  f32x4 wA[8], wB[8];
  short8 aA[4], aB[4];

  auto issue = [&](int b, f32x4 (&wv)[8], short8 (&av)[4]) {
    const int k = b << 5;
    #pragma unroll
    for (int mf = 0; mf < 4; ++mf)
      av[mf] = *(const short8*)(ap + KS16 * mf + k);
    #pragma unroll
    for (int nf = 0; nf < 4; ++nf) {
      wv[2 * nf]     = *(const f32x4*)(wp + KS16 * nf + k);
      wv[2 * nf + 1] = *(const f32x4*)(wp + KS16 * nf + k + 4);
    }
  };
  auto consume = [&](f32x4 (&wv)[8], short8 (&av)[4]) {
    #pragma unroll
    for (int nf = 0; nf < 4; ++nf) {
      short8 bb;
      #pragma unroll
      for (int i = 0; i < 4; ++i) {
        bb[i]     = f2bf(wv[2 * nf][i]);
        bb[4 + i] = f2bf(wv[2 * nf + 1][i]);
      }
      #pragma unroll
      for (int mf = 0; mf < 4; ++mf)
        acc[mf][nf] = __builtin_amdgcn_mfma_f32_16x16x32_bf16(av[mf], bb, acc[mf][nf], 0, 0, 0);
    }
  };

  constexpr int NT = K / 32;           // even (32 or 64)
  issue(0, wA, aA);
  for (int b = 0; b < NT; b += 2) {
    if (b + 1 < NT) issue(b + 1, wB, aB);
    SCHED_FENCE();                     // pin issue-early before consume
    consume(wA, aA);
    if ((b & 3) == 2) __builtin_amdgcn_s_barrier();   // drift bound, raw
    if (b + 2 < NT) issue(b + 2, wA, aA);
    SCHED_FENCE();
    consume(wB, aB);
  }

  // ---- epilogue: per-wave LDS transpose -> full-line f32x4 stores ----
  // acc layout: col = nf*16 + l16, row = mf*16 + lq*4 + r  [m89]
  float bvv[4];
  #pragma unroll
  for (int nf = 0; nf < 4; ++nf) bvv[nf] = bias[n0 + nf * 16 + l16];

  const int rr = lq;
  const int cc = l16 * 4;
  #pragma unroll
  for (int mf = 0; mf < 4; ++mf) {
    #pragma unroll
    for (int nf = 0; nf < 4; ++nf)
      #pragma unroll
      for (int r = 0; r < 4; ++r)
        ep[(lq * 4 + r) * EPS + nf * 16 + l16] = acc[mf][nf][r] + bvv[nf];
    #pragma unroll
    for (int i = 0; i < 4; ++i) {
      f32x4 vv = *(const f32x4*)&ep[(i * 4 + rr) * EPS + cc];
      *(f32x4*)&C[(size_t)(m0 + mf * 16 + i * 4 + rr) * N + n0 + cc] = vv;
    }
  }
}

__global__ __launch_bounds__(512, 2) void gru_gemms_kernel(
    const short* __restrict__ xbf, const short* __restrict__ hbf,
    const float* __restrict__ W_ih, const float* __restrict__ W_hh,
    const float* __restrict__ b_ih, const float* __restrict__ b_hh,
    float* __restrict__ gi, float* __restrict__ gh)
{
  __shared__ float eps[8][16 * EPS];
  const int wv = threadIdx.x >> 6;           // m-group 0..7
  const bool second = blockIdx.x >= 96;
  const int nt = second ? (int)blockIdx.x - 96 : (int)blockIdx.x;
  if (second)
    sgemm_stream<2048>(hbf, W_hh, b_hh, gh, 6144, wv * 64, nt * 64, eps[wv]);
  else
    sgemm_stream<1024>(xbf, W_ih, b_ih, gi, 6144, wv * 64, nt * 64, eps[wv]);
}

__global__ __launch_bounds__(512, 2) void logits_kernel(
    const short* __restrict__ hnbf, const float* __restrict__ fc_W,
    const float* __restrict__ fc_b, float* __restrict__ out)
{
  __shared__ float eps[8][16 * EPS];
  const int wv = threadIdx.x >> 6;           // m-group 0..7
  const int nt = (int)blockIdx.x;            // n-tile 0..499
  sgemm_stream<2048>(hnbf, fc_W, fc_b, out, 32000, wv * 64, nt * 64, eps[wv]);
}

__global__ void prep_kernel(const int* __restrict__ idx,
                            const float* __restrict__ hid,
                            const float* __restrict__ emb,
                            short* __restrict__ xbf, short* __restrict__ hbf)
{
  int i = blockIdx.x * blockDim.x + threadIdx.x;
  const int NX = 512 * 1024 / 4;
  const int NH = 512 * 2048 / 4;
  if (i < NX) {
    int b = i >> 8;
    int c = (i & 255) << 2;
    int row = idx[b];
    f32x4 v = *(const f32x4*)(emb + (size_t)row * 1024 + c);
    short4v o;
    #pragma unroll
    for (int j = 0; j < 4; ++j) o[j] = f2bf(v[j]);
    *(short4v*)(xbf + (size_t)b * 1024 + c) = o;
  } else if (i < NX + NH) {
    int j2 = i - NX;
    f32x4 v = *(const f32x4*)(hid + (size_t)j2 * 4);
    short4v o;
    #pragma unroll
    for (int j = 0; j < 4; ++j) o[j] = f2bf(v[j]);
    *(short4v*)(hbf + (size_t)j2 * 4) = o;
  }
}

__global__ void gates_kernel(const float* __restrict__ gi,
                             const float* __restrict__ gh,
                             const float* __restrict__ hid,
                             float* __restrict__ hnew,
                             short* __restrict__ hnbf)
{
  int i = blockIdx.x * blockDim.x + threadIdx.x;
  int b = i >> 9;
  int c = (i & 511) << 2;
  size_t gbase = (size_t)b * 6144 + c;
  f32x4 gir = *(const f32x4*)(gi + gbase);
  f32x4 giz = *(const f32x4*)(gi + gbase + 2048);
  f32x4 gin = *(const f32x4*)(gi + gbase + 4096);
  f32x4 ghr = *(const f32x4*)(gh + gbase);
  f32x4 ghz = *(const f32x4*)(gh + gbase + 2048);
  f32x4 ghn = *(const f32x4*)(gh + gbase + 4096);
  f32x4 hv  = *(const f32x4*)(hid + (size_t)b * 2048 + c);
  f32x4 hn;
  short4v hb;
  #pragma unroll
  for (int j = 0; j < 4; ++j) {
    float r = 1.f / (1.f + __expf(-(gir[j] + ghr[j])));
    float z = 1.f / (1.f + __expf(-(giz[j] + ghz[j])));
    float n = tanhf(gin[j] + r * ghn[j]);
    float o = (1.f - z) * n + z * hv[j];
    hn[j] = o;
    hb[j] = f2bf(o);
  }
  *(f32x4*)(hnew + (size_t)b * 2048 + c) = hn;
  *(short4v*)(hnbf + (size_t)b * 2048 + c) = hb;
}

extern "C" void kernel_launch(void* const* d_in, const int* in_sizes, int n_in,
                              void* d_out, int out_size, void* d_ws, size_t ws_size,
                              hipStream_t stream)
{
  const int*   idx   = (const int*)d_in[0];
  const float* hid   = (const float*)d_in[1];
  const float* emb   = (const float*)d_in[2];
  const float* W_ih  = (const float*)d_in[3];
  const float* W_hh  = (const float*)d_in[4];
  const float* b_ih  = (const float*)d_in[5];
  const float* b_hh  = (const float*)d_in[6];
  const float* fc_W  = (const float*)d_in[7];
  const float* fc_b  = (const float*)d_in[8];
  float* out = (float*)d_out;

  char* ws = (char*)d_ws;
  short* xbf  = (short*)(ws);
  short* hbf  = (short*)(ws + 1048576);
  short* hnbf = (short*)(ws + 3145728);
  float* gi   = (float*)(ws + 5242880);
  float* gh   = (float*)(ws + 17825792);

  prep_kernel<<<1536, 256, 0, stream>>>(idx, hid, emb, xbf, hbf);
  gru_gemms_kernel<<<192, 512, 0, stream>>>(xbf, hbf, W_ih, W_hh, b_ih, b_hh, gi, gh);
  gates_kernel<<<1024, 256, 0, stream>>>(gi, gh, hid, out + (size_t)512 * 32000, hnbf);
  logits_kernel<<<500, 512, 0, stream>>>(hnbf, fc_W, fc_b, out);
}

// Round 15
// 373.165 us; speedup vs baseline: 1.4596x; 1.4596x over previous
//
#include <hip/hip_runtime.h>
#include <hip/hip_bf16.h>

typedef __attribute__((ext_vector_type(8))) short short8;
typedef __attribute__((ext_vector_type(4))) short short4v;
typedef __attribute__((ext_vector_type(4))) float f32x4;

__device__ __forceinline__ short f2bf(float f) {
  union { __hip_bfloat16 h; short s; } u;
  u.h = __float2bfloat16(f);
  return u.s;
}

#define SCHED_FENCE() __builtin_amdgcn_sched_barrier(0)
#define EPS 68   // epilogue f32 row stride

// C[512,N] = A_bf16[512,K] * W_f32[N,K]^T + bias.  BN=64, BK=64.
// 8 waves; wave w owns rows [w*64..w*64+64); waves share the W panel.
// Per iter (tile b = 64 cols x 64 k):
//   consume(b): 8 ds_read_b128 (bf16 W, R3's zero-conflict swizzle) +
//               64 MFMA, A from regs (loaded LAST iter -> compiler waits
//               vmcnt(2), sparing the W(b+1) reg loads)
//   loadA(b+1) -> same regs (WAR-safe, after MFMAs)
//   loadW(b+2) -> rotating reg set (f32, 2 f32x4/thread)
//   commitW(b+1): cvt f32->bf16 ONCE (8/thread) + one short8 ds_write to
//                 LDS slot (b+1)%3   [compiler waits vmcnt(10) - counted]
//   lgkmcnt(0); s_barrier            [no vmcnt drain at the barrier]
// W reg flight ~1.2 iter (~1900cy > 900 HBM); A flight ~0.8 iter (L2).
// LDS/iter = 32KB read + 4KB write (4x less than f32-in-LDS variants);
// swizzle: lds_short[row*64 + (scol ^ ((row&7)<<3))] - R3-measured clean.
template<int K>
__device__ __forceinline__ void gemm_v15(
    const short* __restrict__ A,
    const float* __restrict__ W,
    const float* __restrict__ bias,
    float* __restrict__ C,
    int N, int n0, char* smem)
{
  constexpr int NT = K / 64;
  short* wl = (short*)smem;                 // 3 slots x 4096 shorts (8KB)

  const int t   = threadIdx.x;
  const int w   = t >> 6;
  const int l   = t & 63;
  const int l16 = l & 15;
  const int lq  = l >> 4;

  // stage addressing: thread t -> W row sv=t>>3, 8 f32 at sk=(t&7)*8
  const int sv = t >> 3;
  const int sk = (t & 7) * 8;
  const float* wp = W + (size_t)(n0 + sv) * K + sk;
  const int woff = sv * 64 + (sk ^ ((sv & 7) << 3));

  const short* ap = A + (size_t)(w * 64 + l16) * K + lq * 8;

  f32x4 acc[4][4];
  #pragma unroll
  for (int i = 0; i < 4; ++i)
    #pragma unroll
    for (int j = 0; j < 4; ++j) {
      f32x4 z = {0.f, 0.f, 0.f, 0.f};
      acc[i][j] = z;
    }

  f32x4 wrA[2], wrB[2];
  short8 a[2][4];                            // [ks][mf], single set

  auto loadW = [&](int tile, f32x4 (&r)[2]) {
    r[0] = *(const f32x4*)(wp + tile * 64);
    r[1] = *(const f32x4*)(wp + tile * 64 + 4);
  };
  auto loadA = [&](int tile) {
    #pragma unroll
    for (int ks = 0; ks < 2; ++ks)
      #pragma unroll
      for (int mf = 0; mf < 4; ++mf)
        a[ks][mf] = *(const short8*)(ap + (size_t)mf * 16 * K
                                        + tile * 64 + ks * 32);
  };
  auto commitW = [&](const f32x4 (&r)[2], int slot) {
    short8 v;
    #pragma unroll
    for (int i = 0; i < 8; ++i) v[i] = f2bf(i < 4 ? r[0][i] : r[1][i - 4]);
    *(short8*)(wl + slot * 4096 + woff) = v;
  };
  auto consume = [&](int slot) {
    const short* lb = wl + slot * 4096;
    #pragma unroll
    for (int ks = 0; ks < 2; ++ks) {
      short8 bb[4];
      #pragma unroll
      for (int nf = 0; nf < 4; ++nf) {
        const int row = nf * 16 + l16;
        bb[nf] = *(const short8*)(lb + row * 64
                                     + ((ks * 32 + lq * 8) ^ ((row & 7) << 3)));
      }
      #pragma unroll
      for (int mf = 0; mf < 4; ++mf)
        #pragma unroll
        for (int nf = 0; nf < 4; ++nf)
          acc[mf][nf] = __builtin_amdgcn_mfma_f32_16x16x32_bf16(
                            a[ks][mf], bb[nf], acc[mf][nf], 0, 0, 0);
    }
  };

  // prologue: W0 -> set A, A0 -> regs, W1 -> set B, commit W0 -> slot 0
  loadW(0, wrA);
  loadA(0);
  loadW(1, wrB);
  commitW(wrA, 0);                      // waits its own regs (counted)
  asm volatile("s_waitcnt lgkmcnt(0)" ::: "memory");
  SCHED_FENCE();
  __builtin_amdgcn_s_barrier();

  int scon = 0;                         // b % 3
  int scom = 1;                         // (b+1) % 3
  for (int b = 0; b < NT; ++b) {
    consume(scon);                      // waits A(b): vmcnt(2), W(b+1) lives
    SCHED_FENCE();
    if (b + 1 < NT) loadA(b + 1);       // overwrite after use (WAR-safe)
    if (b + 2 < NT) loadW(b + 2, (b & 1) ? wrB : wrA);
    SCHED_FENCE();
    if (b + 1 < NT) commitW((b & 1) ? wrA : wrB, scom);  // W(b+1), vmcnt(10)
    asm volatile("s_waitcnt lgkmcnt(0)" ::: "memory");
    SCHED_FENCE();
    __builtin_amdgcn_s_barrier();
    scon = (scon == 2) ? 0 : scon + 1;
    scom = (scom == 2) ? 0 : scom + 1;
  }
  __syncthreads();                       // before aliasing LDS for epilogue

  // ---- epilogue: per-wave LDS transpose -> full-line f32x4 stores ----
  // acc layout: col = nf*16 + l16, row = mf*16 + lq*4 + r  [m89]
  float bvv[4];
  #pragma unroll
  for (int nf = 0; nf < 4; ++nf) bvv[nf] = bias[n0 + nf * 16 + l16];

  float* ep = (float*)(smem) + w * 16 * EPS;
  const int rr = lq;
  const int cc = l16 * 4;
  #pragma unroll
  for (int mf = 0; mf < 4; ++mf) {
    #pragma unroll
    for (int nf = 0; nf < 4; ++nf)
      #pragma unroll
      for (int r = 0; r < 4; ++r)
        ep[(lq * 4 + r) * EPS + nf * 16 + l16] = acc[mf][nf][r] + bvv[nf];
    #pragma unroll
    for (int i = 0; i < 4; ++i) {
      f32x4 vv = *(const f32x4*)&ep[(i * 4 + rr) * EPS + cc];
      *(f32x4*)&C[(size_t)(w * 64 + mf * 16 + i * 4 + rr) * N + n0 + cc] = vv;
    }
  }
}

__global__ __launch_bounds__(512, 4) void gru_gemms_kernel(
    const short* __restrict__ xbf, const short* __restrict__ hbf,
    const float* __restrict__ W_ih, const float* __restrict__ W_hh,
    const float* __restrict__ b_ih, const float* __restrict__ b_hh,
    float* __restrict__ gi, float* __restrict__ gh)
{
  __shared__ __align__(16) char smem[34816];   // max(3x8KB ring, epilogue)
  const bool second = blockIdx.x >= 96;
  const int nb = second ? (int)blockIdx.x - 96 : (int)blockIdx.x;
  if (second)
    gemm_v15<2048>(hbf, W_hh, b_hh, gh, 6144, nb * 64, smem);
  else
    gemm_v15<1024>(xbf, W_ih, b_ih, gi, 6144, nb * 64, smem);
}

__global__ __launch_bounds__(512, 4) void logits_kernel(
    const short* __restrict__ hnbf, const float* __restrict__ fc_W,
    const float* __restrict__ fc_b, float* __restrict__ out)
{
  __shared__ __align__(16) char smem[34816];
  gemm_v15<2048>(hnbf, fc_W, fc_b, out, 32000, (int)blockIdx.x * 64, smem);
}

__global__ void prep_kernel(const int* __restrict__ idx,
                            const float* __restrict__ hid,
                            const float* __restrict__ emb,
                            short* __restrict__ xbf, short* __restrict__ hbf)
{
  int i = blockIdx.x * blockDim.x + threadIdx.x;
  const int NX = 512 * 1024 / 4;
  const int NH = 512 * 2048 / 4;
  if (i < NX) {
    int b = i >> 8;
    int c = (i & 255) << 2;
    int row = idx[b];
    f32x4 v = *(const f32x4*)(emb + (size_t)row * 1024 + c);
    short4v o;
    #pragma unroll
    for (int j = 0; j < 4; ++j) o[j] = f2bf(v[j]);
    *(short4v*)(xbf + (size_t)b * 1024 + c) = o;
  } else if (i < NX + NH) {
    int j2 = i - NX;
    f32x4 v = *(const f32x4*)(hid + (size_t)j2 * 4);
    short4v o;
    #pragma unroll
    for (int j = 0; j < 4; ++j) o[j] = f2bf(v[j]);
    *(short4v*)(hbf + (size_t)j2 * 4) = o;
  }
}

__global__ void gates_kernel(const float* __restrict__ gi,
                             const float* __restrict__ gh,
                             const float* __restrict__ hid,
                             float* __restrict__ hnew,
                             short* __restrict__ hnbf)
{
  int i = blockIdx.x * blockDim.x + threadIdx.x;
  int b = i >> 9;
  int c = (i & 511) << 2;
  size_t gbase = (size_t)b * 6144 + c;
  f32x4 gir = *(const f32x4*)(gi + gbase);
  f32x4 giz = *(const f32x4*)(gi + gbase + 2048);
  f32x4 gin = *(const f32x4*)(gi + gbase + 4096);
  f32x4 ghr = *(const f32x4*)(gh + gbase);
  f32x4 ghz = *(const f32x4*)(gh + gbase + 2048);
  f32x4 ghn = *(const f32x4*)(gh + gbase + 4096);
  f32x4 hv  = *(const f32x4*)(hid + (size_t)b * 2048 + c);
  f32x4 hn;
  short4v hb;
  #pragma unroll
  for (int j = 0; j < 4; ++j) {
    float r = 1.f / (1.f + __expf(-(gir[j] + ghr[j])));
    float z = 1.f / (1.f + __expf(-(giz[j] + ghz[j])));
    float n = tanhf(gin[j] + r * ghn[j]);
    float o = (1.f - z) * n + z * hv[j];
    hn[j] = o;
    hb[j] = f2bf(o);
  }
  *(f32x4*)(hnew + (size_t)b * 2048 + c) = hn;
  *(short4v*)(hnbf + (size_t)b * 2048 + c) = hb;
}

extern "C" void kernel_launch(void* const* d_in, const int* in_sizes, int n_in,
                              void* d_out, int out_size, void* d_ws, size_t ws_size,
                              hipStream_t stream)
{
  const int*   idx   = (const int*)d_in[0];
  const float* hid   = (const float*)d_in[1];
  const float* emb   = (const float*)d_in[2];
  const float* W_ih  = (const float*)d_in[3];
  const float* W_hh  = (const float*)d_in[4];
  const float* b_ih  = (const float*)d_in[5];
  const float* b_hh  = (const float*)d_in[6];
  const float* fc_W  = (const float*)d_in[7];
  const float* fc_b  = (const float*)d_in[8];
  float* out = (float*)d_out;

  char* ws = (char*)d_ws;
  short* xbf  = (short*)(ws);
  short* hbf  = (short*)(ws + 1048576);
  short* hnbf = (short*)(ws + 3145728);
  float* gi   = (float*)(ws + 5242880);
  float* gh   = (float*)(ws + 17825792);

  prep_kernel<<<1536, 256, 0, stream>>>(idx, hid, emb, xbf, hbf);
  gru_gemms_kernel<<<192, 512, 0, stream>>>(xbf, hbf, W_ih, W_hh, b_ih, b_hh, gi, gh);
  gates_kernel<<<1024, 256, 0, stream>>>(gi, gh, hid, out + (size_t)512 * 32000, hnbf);
  logits_kernel<<<500, 512, 0, stream>>>(hnbf, fc_W, fc_b, out);
}